// Round 1
// 335.146 us; speedup vs baseline: 1.0781x; 1.0781x over previous
//
#include <hip/hip_runtime.h>
#include <hip/hip_bf16.h>
#include <math.h>

#define FDIM 15
#define FPAD 16
#define NEG_SLOPE 0.2f
// dst-buckets of 256 nodes each: bucket = dst >> 8, local = dst & 255
#define BSH 8
#define BWID 256
// R5/R9 lesson: per-(block,bucket) chunk contiguity rules. 256 blocks ->
// ~33 edges (132B) per chunk. 1024 thr/block supplies occupancy.
#define HB_GRID 256
#define HB_BLK 1024

typedef _Float16 half_t;

__device__ __forceinline__ float leaky(float e) {
  return fmaxf(NEG_SLOPE * e, e);   // valid for slope<1
}

__global__ void k_zero(int* __restrict__ p, int n) {
  int i = blockIdx.x * blockDim.x + threadIdx.x;
  if (i < n) p[i] = 0;
}

// ---- bucket histogram over all edges (incl. self loops) ----
__global__ void k_bhist(const int* __restrict__ dstI, int* __restrict__ bcnt,
                        int n_tot, int n_real, int NB) {
  __shared__ int hist[512];
  int tid = threadIdx.x;
  for (int i = tid; i < NB; i += blockDim.x) hist[i] = 0;
  __syncthreads();
  int stride = gridDim.x * blockDim.x;
  for (int i = blockIdx.x * blockDim.x + tid; i < n_tot; i += stride) {
    int d = (i < n_real) ? dstI[i] : (i - n_real);
    atomicAdd(&hist[d >> BSH], 1);
  }
  __syncthreads();
  for (int i = tid; i < NB; i += blockDim.x)
    if (hist[i]) atomicAdd(&bcnt[i], hist[i]);
}

// ---- exclusive scan of bucket counts (single block, 512 thr) ----
__global__ void k_bscan(const int* __restrict__ bcnt, int* __restrict__ boff,
                        int* __restrict__ bcur, int* __restrict__ rowptr,
                        int NB, int N, int total) {
  __shared__ int s[512];
  int tid = threadIdx.x;
  int v = (tid < NB) ? bcnt[tid] : 0;
  s[tid] = v;
  __syncthreads();
  for (int off = 1; off < 512; off <<= 1) {
    int add = (tid >= off) ? s[tid - off] : 0;
    __syncthreads();
    s[tid] += add;
    __syncthreads();
  }
  if (tid < NB) { int e = s[tid] - v; boff[tid] = e; bcur[tid] = e; }
  if (tid == NB - 1) boff[NB] = s[tid];
  if (tid == 0) rowptr[N] = total;
}

// ---- partition edges into dst-buckets, packed (src<<8 | dst&255) ----
__global__ void k_bpart(const int* __restrict__ srcI, const int* __restrict__ dstI,
                        int* __restrict__ bcur, int* __restrict__ bbuf,
                        int n_tot, int n_real, int NB) {
  __shared__ int hist[512];
  __shared__ int base[512];
  int tid = threadIdx.x;
  for (int i = tid; i < NB; i += blockDim.x) hist[i] = 0;
  __syncthreads();
  int stride = gridDim.x * blockDim.x;
  int g0 = blockIdx.x * blockDim.x + tid;
  for (int i = g0; i < n_tot; i += stride) {
    int d = (i < n_real) ? dstI[i] : (i - n_real);
    atomicAdd(&hist[d >> BSH], 1);
  }
  __syncthreads();
  for (int i = tid; i < NB; i += blockDim.x)
    base[i] = hist[i] ? atomicAdd(&bcur[i], hist[i]) : 0;
  __syncthreads();
  for (int i = tid; i < NB; i += blockDim.x) hist[i] = 0;
  __syncthreads();
  for (int i = g0; i < n_tot; i += stride) {
    int s, d;
    if (i < n_real) { s = srcI[i]; d = dstI[i]; }
    else { s = d = i - n_real; }
    int b = d >> BSH;
    int p = base[b] + atomicAdd(&hist[b], 1);
    bbuf[p] = (s << BSH) | (d & (BWID - 1));
  }
}

// ---- per-bucket: per-dst hist -> scan -> rowptr + csr scatter (512 thr) ----
// csr stores PRE-SCALED byte offsets (src*32) for k_gat's hp gathers.
__global__ void k_bbuild(const int* __restrict__ boff, const int* __restrict__ bbuf,
                         int* __restrict__ rowptr, int* __restrict__ csr, int N) {
  __shared__ int hist[BWID];
  __shared__ int sc[BWID];
  int b = blockIdx.x;
  int tid = threadIdx.x;  // 512
  int base_dst = b << BSH;
  int nd = min(BWID, N - base_dst);
  int s0 = boff[b], s1 = boff[b + 1];
  if (tid < BWID) hist[tid] = 0;
  __syncthreads();
  for (int j = s0 + tid; j < s1; j += 512)
    atomicAdd(&hist[bbuf[j] & (BWID - 1)], 1);
  __syncthreads();
  int v = 0;
  if (tid < BWID) { v = hist[tid]; sc[tid] = v; }
  __syncthreads();
  for (int off = 1; off < BWID; off <<= 1) {
    int add = 0;
    if (tid < BWID && tid >= off) add = sc[tid - off];
    __syncthreads();
    if (tid < BWID) sc[tid] += add;
    __syncthreads();
  }
  if (tid < nd) rowptr[base_dst + tid] = s0 + sc[tid] - v;
  __syncthreads();
  if (tid < BWID) hist[tid] = sc[tid] - v;
  __syncthreads();
  for (int j = s0 + tid; j < s1; j += 512) {
    int e = bbuf[j];
    int dl = e & (BWID - 1);
    int p = s0 + atomicAdd(&hist[dl], 1);
    csr[p] = (e >> BSH) << 5;   // src * 32 bytes
  }
}

// ---- h = in @ W (fp16, as packed in slot 15) ; ad_ fp32 (layer 0 only) ----
__global__ void k_transform(const float* __restrict__ in, int ld_in,
                            const float* __restrict__ W,
                            const float* __restrict__ a_s,
                            const float* __restrict__ a_d,
                            half_t* __restrict__ hp,
                            float* __restrict__ ad_,
                            int n_nodes) {
  __shared__ float Ws[FDIM * FDIM];
  __shared__ float asv[FDIM], adv[FDIM];
  int tid = threadIdx.x;
  if (tid < FDIM * FDIM) Ws[tid] = W[tid];
  if (tid < FDIM) { asv[tid] = a_s[tid]; adv[tid] = a_d[tid]; }
  __syncthreads();
  int n = blockIdx.x * blockDim.x + tid;
  if (n >= n_nodes) return;
  float xin[FDIM];
#pragma unroll
  for (int j = 0; j < FDIM; ++j) xin[j] = in[n * ld_in + j];
  float sa = 0.f, da = 0.f;
  half_t hrow[FPAD];
#pragma unroll
  for (int o = 0; o < FDIM; ++o) {
    float acc = 0.f;
#pragma unroll
    for (int k = 0; k < FDIM; ++k) acc += xin[k] * Ws[k * FDIM + o];
    hrow[o] = (half_t)acc;
    sa += acc * asv[o];
    da += acc * adv[o];
  }
  hrow[FDIM] = (half_t)sa;
  ad_[n] = da;
  float4 w0, w1;
  __builtin_memcpy(&w0, &hrow[0], 16);
  __builtin_memcpy(&w1, &hrow[8], 16);
  float4* dst = (float4*)(hp + (size_t)n * FPAD);
  dst[0] = w0;
  dst[1] = w1;
}

// ---- annotation-MLP stage rider: 8-way explicit ILP (R16 lesson: rider
// block lifetime = displacement window; R11 lesson: only explicit scalar
// loads produce loads-in-flight on this compiler) ----
__device__ __forceinline__ void mlp_rider(int g, int tid, int nthreads,
                                          const float* __restrict__ mIn,
                                          const float* __restrict__ mW,
                                          const float* __restrict__ mB,
                                          float* __restrict__ mOut,
                                          int Nout, int mAct,
                                          float* mins) {
  for (int k = tid; k < 300; k += nthreads) mins[k] = mIn[(size_t)g * 300 + k];
  __syncthreads();
  int j1 = tid;
  int j2 = tid + nthreads;
  bool p1 = (j1 < Nout), p2 = (j2 < Nout);
  if (!p1) return;
  float a0 = 0.f, a1 = 0.f, a2 = 0.f, a3 = 0.f;
  float a4 = 0.f, a5 = 0.f, a6 = 0.f, a7 = 0.f;
  float b0 = 0.f, b1 = 0.f, b2 = 0.f, b3 = 0.f;
  float b4 = 0.f, b5 = 0.f, b6 = 0.f, b7 = 0.f;
  int k = 0;
  for (; k + 7 < 300; k += 8) {
    float i0 = mins[k],     i1 = mins[k + 1], i2 = mins[k + 2], i3 = mins[k + 3];
    float i4 = mins[k + 4], i5 = mins[k + 5], i6 = mins[k + 6], i7 = mins[k + 7];
    float w0 = mW[k * Nout + j1];
    float w1 = mW[(k + 1) * Nout + j1];
    float w2 = mW[(k + 2) * Nout + j1];
    float w3 = mW[(k + 3) * Nout + j1];
    float w4 = mW[(k + 4) * Nout + j1];
    float w5 = mW[(k + 5) * Nout + j1];
    float w6 = mW[(k + 6) * Nout + j1];
    float w7 = mW[(k + 7) * Nout + j1];
    a0 += i0 * w0; a1 += i1 * w1; a2 += i2 * w2; a3 += i3 * w3;
    a4 += i4 * w4; a5 += i5 * w5; a6 += i6 * w6; a7 += i7 * w7;
    if (p2) {
      float v0 = mW[k * Nout + j2];
      float v1 = mW[(k + 1) * Nout + j2];
      float v2 = mW[(k + 2) * Nout + j2];
      float v3 = mW[(k + 3) * Nout + j2];
      float v4 = mW[(k + 4) * Nout + j2];
      float v5 = mW[(k + 5) * Nout + j2];
      float v6 = mW[(k + 6) * Nout + j2];
      float v7 = mW[(k + 7) * Nout + j2];
      b0 += i0 * v0; b1 += i1 * v1; b2 += i2 * v2; b3 += i3 * v3;
      b4 += i4 * v4; b5 += i5 * v5; b6 += i6 * v6; b7 += i7 * v7;
    }
  }
  for (; k < 300; ++k) {
    float ik = mins[k];
    a0 += ik * mW[k * Nout + j1];
    if (p2) b0 += ik * mW[k * Nout + j2];
  }
  float r1 = mB[j1] + ((a0 + a1) + (a2 + a3)) + ((a4 + a5) + (a6 + a7));
  if (mAct == 1) r1 = fmaxf(r1, 0.f);
  else if (mAct == 2) r1 = 1.f / (1.f + expf(-r1));
  mOut[(size_t)g * Nout + j1] = r1;
  if (p2) {
    float r2 = mB[j2] + ((b0 + b1) + (b2 + b3)) + ((b4 + b5) + (b6 + b7));
    if (mAct == 1) r2 = fmaxf(r2, 0.f);
    else if (mAct == 2) r2 = 1.f / (1.f + expf(-r2));
    mOut[(size_t)g * Nout + j2] = r2;
  }
}

// ---- fused GAT aggregate + FFN (+ next-layer transform) + MLP rider ----
// R17 edge-loop reorg: 4 lanes per edge, 8B dwordx2 loads, 8 edges per
// 16-lane group per step (masked tail folded into main loop). Replaces
// the 16-lanes-per-edge 2B-gather loop (issue-bound: 2.7 VALU + 0.5 VMEM
// instr/edge -> ~1.2 VALU + 0.125 VMEM instr/edge).
__global__ void k_gat(const int* __restrict__ rowptr, const int* __restrict__ csrB,
                      const half_t* __restrict__ hp, const float* __restrict__ ad_,
                      const float* __restrict__ cb, const float* __restrict__ fW,
                      const float* __restrict__ fb,
                      const float* __restrict__ nW, const float* __restrict__ nas,
                      const float* __restrict__ nad,
                      half_t* __restrict__ hp2, float* __restrict__ ad2,
                      float* __restrict__ fout,
                      const float* __restrict__ mIn, const float* __restrict__ mW,
                      const float* __restrict__ mB, float* __restrict__ mOut,
                      int mNout, int mAct, int mlpG,
                      int n_nodes, int do_relu, int fuse) {
  __shared__ float Ws[FDIM * FDIM];
  __shared__ float W2s[FDIM * FDIM];
  __shared__ float cbv[FDIM], fbv[FDIM], as2v[FDIM], ad2v[FDIM];
  __shared__ float aggT[16][16];
  __shared__ float outT[16][16];
  __shared__ float mins[304];
  int tid = threadIdx.x;

  if ((int)blockIdx.x < mlpG) {
    mlp_rider(blockIdx.x, tid, blockDim.x, mIn, mW, mB, mOut, mNout, mAct, mins);
    return;
  }

  if (tid < FDIM * FDIM) Ws[tid] = fW[tid];
  if (tid < FDIM) { cbv[tid] = cb[tid]; fbv[tid] = fb[tid]; }
  if (fuse) {
    if (tid < FDIM * FDIM) W2s[tid] = nW[tid];
    if (tid < FDIM) { as2v[tid] = nas[tid]; ad2v[tid] = nad[tid]; }
  }
  __syncthreads();
  int dl = tid >> 4;          // local dst 0..15
  int f  = tid & 15;          // lane-in-group
  int e4 = f >> 2;            // edge slot 0..3
  int c  = f & 3;             // 4-half chunk 0..3 (chunk 3 holds slot 15 = sa)
  int d  = ((int)blockIdx.x - mlpG) * 16 + dl;
  float r0 = 0.f, r1 = 0.f, r2 = 0.f, r3 = 0.f;
  if (d < n_nodes) {
    int rs = rowptr[d], re = rowptr[d + 1];   // re > rs always (self loop)
    float adv = ad_[d];
    const char* hb = (const char*)hp;
    int co = c << 3;
    int srcl = f | 3;         // bpermute source: c==3 lane of my edge slot
    float acc0 = 0.f, acc1 = 0.f, acc2 = 0.f, acc3 = 0.f, den = 0.f;
    for (int j = rs; j < re; j += 8) {
      int i0 = j + e4;
      int i1 = i0 + 4;
      int o0 = csrB[i0 < re ? i0 : re - 1];
      int o1 = csrB[i1 < re ? i1 : re - 1];
      uint2 u0 = *(const uint2*)(hb + o0 + co);
      uint2 u1 = *(const uint2*)(hb + o1 + co);
      half_t h0[4], h1[4];
      __builtin_memcpy(h0, &u0, 8);
      __builtin_memcpy(h1, &u1, 8);
      float a0 = (float)h0[0], a1 = (float)h0[1], a2 = (float)h0[2], a3 = (float)h0[3];
      float b0 = (float)h1[0], b1 = (float)h1[1], b2 = (float)h1[2], b3 = (float)h1[3];
      float s0 = __shfl(a3, srcl, 16);
      float s1 = __shfl(b3, srcl, 16);
      float w0 = (i0 < re) ? __expf(leaky(s0 + adv)) : 0.f;
      float w1 = (i1 < re) ? __expf(leaky(s1 + adv)) : 0.f;
      den  += w0 + w1;
      acc0 += a0 * w0 + b0 * w1;
      acc1 += a1 * w0 + b1 * w1;
      acc2 += a2 * w0 + b2 * w1;
      acc3 += a3 * w0 + b3 * w1;
    }
    // reduce across the 4 edge slots (xor bits 2..3 of lane-in-group)
    den  += __shfl_xor(den,  4, 16);
    acc0 += __shfl_xor(acc0, 4, 16);
    acc1 += __shfl_xor(acc1, 4, 16);
    acc2 += __shfl_xor(acc2, 4, 16);
    acc3 += __shfl_xor(acc3, 4, 16);
    den  += __shfl_xor(den,  8, 16);
    acc0 += __shfl_xor(acc0, 8, 16);
    acc1 += __shfl_xor(acc1, 8, 16);
    acc2 += __shfl_xor(acc2, 8, 16);
    acc3 += __shfl_xor(acc3, 8, 16);
    float inv = 1.f / (den + 1e-16f);
    r0 = acc0 * inv; r1 = acc1 * inv; r2 = acc2 * inv; r3 = acc3 * inv;
  }
  if (e4 == 0) {
    int base = c << 2;
    aggT[dl][base]     = r0 + cbv[base];
    aggT[dl][base + 1] = r1 + cbv[base + 1];
    aggT[dl][base + 2] = r2 + cbv[base + 2];
    aggT[dl][base + 3] = (base + 3 < FDIM) ? (r3 + cbv[base + 3]) : 0.f;
  }
  __syncthreads();
  int o = f;
  float ffn = 0.f;
  if (o < FDIM) {
    ffn = fbv[o];
#pragma unroll
    for (int k = 0; k < FDIM; ++k) ffn += aggT[dl][k] * Ws[k * FDIM + o];
    if (do_relu) ffn = fmaxf(ffn, 0.f);
  }
  if (!fuse) {
    if (d < n_nodes) fout[d * FPAD + o] = (o < FDIM) ? ffn : 0.f;
    return;
  }
  // ---- fused next-layer transform: h2 = out @ nW ; sa2/da2 reductions ----
  outT[dl][o] = ffn;   // o==15 lane wrote ffn=0
  __syncthreads();
  if (d < n_nodes) {
    float h2 = 0.f;
    if (o < FDIM) {
#pragma unroll
      for (int k = 0; k < FDIM; ++k) h2 += outT[dl][k] * W2s[k * FDIM + o];
    }
    float pa = (o < FDIM) ? h2 * as2v[o] : 0.f;
    float pd = (o < FDIM) ? h2 * ad2v[o] : 0.f;
#pragma unroll
    for (int k = 8; k; k >>= 1) {
      pa += __shfl_xor(pa, k, 16);
      pd += __shfl_xor(pd, k, 16);
    }
    hp2[(size_t)d * FPAD + o] = (half_t)((o < FDIM) ? h2 : pa);
    if (o == 0) ad2[d] = pd;
  }
}

// ---- pooling + s4 rider (xann = sigmoidActs @ aW4 + ab4) ----
__device__ __forceinline__ int lowerb(const int* __restrict__ a, int n, int key) {
  int lo = 0, hi = n;
  while (lo < hi) { int mid = (lo + hi) >> 1; if (a[mid] < key) lo = mid + 1; else hi = mid; }
  return lo;
}

__global__ void k_pool(const float* __restrict__ fout, const int* __restrict__ batch,
                       float* __restrict__ pooled,
                       const float* __restrict__ acts,
                       const float* __restrict__ aW4, const float* __restrict__ ab4,
                       float* __restrict__ xann,
                       int n_nodes, int Gn) {
  __shared__ float ss[256], sm[256];
  __shared__ float mins[304];
  int tid = threadIdx.x;
  if ((int)blockIdx.x < Gn) {
    mlp_rider(blockIdx.x, tid, blockDim.x, acts, aW4, ab4, xann, 45, 0, mins);
    return;
  }
  int g = blockIdx.x - Gn;
  int s = lowerb(batch, n_nodes, g);
  int e = lowerb(batch, n_nodes, g + 1);
  int f = tid & 15;
  float sum = 0.f, mx = -INFINITY;
  for (int n = s + (tid >> 4); n < e; n += 16) {
    float v = fout[n * FPAD + f];
    sum += v;
    mx = fmaxf(mx, v);
  }
  ss[tid] = sum; sm[tid] = mx;
  __syncthreads();
  for (int step = 128; step >= 16; step >>= 1) {
    if (tid < step) { ss[tid] += ss[tid + step]; sm[tid] = fmaxf(sm[tid], sm[tid + step]); }
    __syncthreads();
  }
  if (tid < FDIM) {
    float cnt = (float)(e - s);
    float sv = ss[tid];
    pooled[g * 45 + tid] = sv;
    pooled[g * 45 + 15 + tid] = sm[tid];
    pooled[g * 45 + 30 + tid] = sv / fmaxf(cnt, 1.f);
  }
}

// ---- head: z=[pooled,xann] -> relu(z@m1W+m1b) -> sigmoid(@m2W+m2b) ----
__global__ void k_final(const float* __restrict__ pooled, const float* __restrict__ xann,
                        const float* __restrict__ m1W, const float* __restrict__ m1b,
                        const float* __restrict__ m2W, const float* __restrict__ m2b,
                        float* __restrict__ out) {
  __shared__ float z[90];
  __shared__ float z2[90];
  __shared__ float ps[128];
  int g = blockIdx.x;
  int t = threadIdx.x;  // 128
  if (t < 45) z[t] = pooled[g * 45 + t];
  else if (t < 90) z[t] = xann[g * 45 + (t - 45)];
  __syncthreads();
  if (t < 90) {
    float a0 = 0.f, a1 = 0.f;
    for (int k = 0; k < 90; k += 2) {
      float w0 = m1W[k * 90 + t];
      float w1 = m1W[(k + 1) * 90 + t];
      a0 += z[k] * w0; a1 += z[k + 1] * w1;
    }
    z2[t] = fmaxf(m1b[t] + a0 + a1, 0.f);
  }
  __syncthreads();
  if (t < 90) ps[t] = z2[t] * m2W[t];
  else ps[t] = 0.f;
  __syncthreads();
  if (t < 64) {
    float v = ps[t] + ps[t + 64];
#pragma unroll
    for (int k2 = 32; k2; k2 >>= 1) v += __shfl_xor(v, k2, 64);
    if (t == 0) out[g] = 1.f / (1.f + expf(-(v + m2b[0])));
  }
}

extern "C" void kernel_launch(void* const* d_in, const int* in_sizes, int n_in,
                              void* d_out, int out_size, void* d_ws, size_t ws_size,
                              hipStream_t stream) {
  const float* x   = (const float*)d_in[0];
  const int* ei    = (const int*)d_in[1];
  const int* batch = (const int*)d_in[2];
  const float* xA  = (const float*)d_in[3];

  const int N = in_sizes[0] / FDIM;
  const int E = in_sizes[1] / 2;
  const int G = in_sizes[3] / 300;
  const int ET = E + N;
  const int NB = (N + BWID - 1) >> BSH;   // dst buckets (<=512 for N<=131072)

  const int* srcI = ei;
  const int* dstI = ei + E;

  // ---- workspace layout (4-byte words) ----
  float* ws = (float*)d_ws;
  size_t layerW = (size_t)34 * N;  // hpA(8N)+hpB(8N)+adA(N)+adB(N)+fout(16N)
  size_t uSize = layerW > (size_t)ET ? layerW : (size_t)ET;
  size_t off = 0;
  int*    bbuf = (int*)(ws + off);
  half_t* hpA  = (half_t*)(ws + off);
  half_t* hpB  = (half_t*)(ws + off + (size_t)8 * N);
  float*  adA  = ws + off + (size_t)16 * N;
  float*  adB  = ws + off + (size_t)17 * N;
  float*  fout = ws + off + (size_t)18 * N;
  off += uSize;
  int*   rowptr = (int*)(ws + off); off += N + 1;
  int*   csr    = (int*)(ws + off); off += (size_t)ET;
  int*   bcnt   = (int*)(ws + off); off += 516;
  int*   boff   = (int*)(ws + off); off += 516;
  int*   bcur   = (int*)(ws + off); off += 516;
  float* pooled = ws + off; off += (size_t)G * 45;
  float* a1     = ws + off; off += (size_t)G * 300;
  float* a2     = ws + off; off += (size_t)G * 300;
  float* xann   = ws + off; off += (size_t)G * 45;

  const int B = 256;
  const int gN = (N + B - 1) / B;

  // ---- bucketed CSR build (R15 two-pass: 43us proven; R16 single-pass lost) --
  k_zero<<<(NB + B - 1) / B, B, 0, stream>>>(bcnt, NB);
  k_bhist<<<HB_GRID, HB_BLK, 0, stream>>>(dstI, bcnt, ET, E, NB);
  k_bscan<<<1, 512, 0, stream>>>(bcnt, boff, bcur, rowptr, NB, N, ET);
  k_bpart<<<HB_GRID, HB_BLK, 0, stream>>>(srcI, dstI, bcur, bbuf, ET, E, NB);
  k_bbuild<<<NB, 512, 0, stream>>>(boff, bbuf, rowptr, csr, N);

  // ---- weights ----
  const float* cW1  = (const float*)d_in[4];
  const float* cas1 = (const float*)d_in[5];
  const float* cad1 = (const float*)d_in[6];
  const float* cb1  = (const float*)d_in[7];
  const float* fW1  = (const float*)d_in[8];
  const float* fb1  = (const float*)d_in[9];
  const float* cW2  = (const float*)d_in[10];
  const float* cas2 = (const float*)d_in[11];
  const float* cad2 = (const float*)d_in[12];
  const float* cb2  = (const float*)d_in[13];
  const float* fW2  = (const float*)d_in[14];
  const float* fb2  = (const float*)d_in[15];
  const float* cW3  = (const float*)d_in[16];
  const float* cas3 = (const float*)d_in[17];
  const float* cad3 = (const float*)d_in[18];
  const float* cb3  = (const float*)d_in[19];
  const float* fW3  = (const float*)d_in[20];
  const float* fb3  = (const float*)d_in[21];
  const float* m1W  = (const float*)d_in[22];
  const float* m1b  = (const float*)d_in[23];
  const float* aW1  = (const float*)d_in[24];
  const float* ab1  = (const float*)d_in[25];
  const float* aW2  = (const float*)d_in[26];
  const float* ab2  = (const float*)d_in[27];
  const float* aW3  = (const float*)d_in[28];
  const float* ab3  = (const float*)d_in[29];
  const float* aW4  = (const float*)d_in[30];
  const float* ab4  = (const float*)d_in[31];
  const float* m2W  = (const float*)d_in[32];
  const float* m2b  = (const float*)d_in[33];

  // ---- 3 GAT layers, each carrying one annotation-MLP stage (R15 placement) --
  const int gGat = (N + 15) / 16;
  k_transform<<<gN, B, 0, stream>>>(x, FDIM, cW1, cas1, cad1, hpA, adA, N);
  k_gat<<<gGat + G, B, 0, stream>>>(rowptr, csr, hpA, adA, cb1, fW1, fb1,
                                    cW2, cas2, cad2, hpB, adB, nullptr,
                                    xA, aW1, ab1, a1, 300, 1, G,
                                    N, 1, 1);
  k_gat<<<gGat + G, B, 0, stream>>>(rowptr, csr, hpB, adB, cb2, fW2, fb2,
                                    cW3, cas3, cad3, hpA, adA, nullptr,
                                    a1, aW2, ab2, a2, 300, 1, G,
                                    N, 1, 1);
  k_gat<<<gGat + G, B, 0, stream>>>(rowptr, csr, hpA, adA, cb3, fW3, fb3,
                                    nullptr, nullptr, nullptr, nullptr, nullptr, fout,
                                    a2, aW3, ab3, a1, 300, 2, G,
                                    N, 0, 0);

  // ---- pooling + s4 rider ----
  k_pool<<<2 * G, B, 0, stream>>>(fout, batch, pooled, a1, aW4, ab4, xann, N, G);

  // ---- head ----
  k_final<<<G, 128, 0, stream>>>(pooled, xann, m1W, m1b, m2W, m2b, (float*)d_out);
}

// Round 2
// 323.703 us; speedup vs baseline: 1.1162x; 1.0353x over previous
//
#include <hip/hip_runtime.h>
#include <hip/hip_bf16.h>
#include <math.h>

#define FDIM 15
#define FPAD 16
#define NEG_SLOPE 0.2f
// dst-buckets of 256 nodes each: bucket = dst >> 8, local = dst & 255
#define BSH 8
#define BWID 256
// R5/R9 lesson: per-(block,bucket) chunk contiguity rules. 256 blocks ->
// ~33 edges (132B) per chunk. 1024 thr/block supplies occupancy.
#define HB_GRID 256
#define HB_BLK 1024

typedef _Float16 half_t;

__device__ __forceinline__ float leaky(float e) {
  return fmaxf(NEG_SLOPE * e, e);   // valid for slope<1
}

__global__ void k_zero(int* __restrict__ p, int n) {
  int i = blockIdx.x * blockDim.x + threadIdx.x;
  if (i < n) p[i] = 0;
}

// ---- bucket histogram over all edges (incl. self loops) ----
__global__ void k_bhist(const int* __restrict__ dstI, int* __restrict__ bcnt,
                        int n_tot, int n_real, int NB) {
  __shared__ int hist[512];
  int tid = threadIdx.x;
  for (int i = tid; i < NB; i += blockDim.x) hist[i] = 0;
  __syncthreads();
  int stride = gridDim.x * blockDim.x;
  for (int i = blockIdx.x * blockDim.x + tid; i < n_tot; i += stride) {
    int d = (i < n_real) ? dstI[i] : (i - n_real);
    atomicAdd(&hist[d >> BSH], 1);
  }
  __syncthreads();
  for (int i = tid; i < NB; i += blockDim.x)
    if (hist[i]) atomicAdd(&bcnt[i], hist[i]);
}

// ---- exclusive scan of bucket counts (single block, 512 thr) ----
__global__ void k_bscan(const int* __restrict__ bcnt, int* __restrict__ boff,
                        int* __restrict__ bcur, int* __restrict__ rowptr,
                        int NB, int N, int total) {
  __shared__ int s[512];
  int tid = threadIdx.x;
  int v = (tid < NB) ? bcnt[tid] : 0;
  s[tid] = v;
  __syncthreads();
  for (int off = 1; off < 512; off <<= 1) {
    int add = (tid >= off) ? s[tid - off] : 0;
    __syncthreads();
    s[tid] += add;
    __syncthreads();
  }
  if (tid < NB) { int e = s[tid] - v; boff[tid] = e; bcur[tid] = e; }
  if (tid == NB - 1) boff[NB] = s[tid];
  if (tid == 0) rowptr[N] = total;
}

// ---- partition edges into dst-buckets, packed (src<<8 | dst&255) ----
__global__ void k_bpart(const int* __restrict__ srcI, const int* __restrict__ dstI,
                        int* __restrict__ bcur, int* __restrict__ bbuf,
                        int n_tot, int n_real, int NB) {
  __shared__ int hist[512];
  __shared__ int base[512];
  int tid = threadIdx.x;
  for (int i = tid; i < NB; i += blockDim.x) hist[i] = 0;
  __syncthreads();
  int stride = gridDim.x * blockDim.x;
  int g0 = blockIdx.x * blockDim.x + tid;
  for (int i = g0; i < n_tot; i += stride) {
    int d = (i < n_real) ? dstI[i] : (i - n_real);
    atomicAdd(&hist[d >> BSH], 1);
  }
  __syncthreads();
  for (int i = tid; i < NB; i += blockDim.x)
    base[i] = hist[i] ? atomicAdd(&bcur[i], hist[i]) : 0;
  __syncthreads();
  for (int i = tid; i < NB; i += blockDim.x) hist[i] = 0;
  __syncthreads();
  for (int i = g0; i < n_tot; i += stride) {
    int s, d;
    if (i < n_real) { s = srcI[i]; d = dstI[i]; }
    else { s = d = i - n_real; }
    int b = d >> BSH;
    int p = base[b] + atomicAdd(&hist[b], 1);
    bbuf[p] = (s << BSH) | (d & (BWID - 1));
  }
}

// ---- per-bucket: per-dst hist -> scan -> rowptr + csr scatter (512 thr) ----
// csr stores PRE-SCALED byte offsets (src*32) for k_gat's hp gathers.
__global__ void k_bbuild(const int* __restrict__ boff, const int* __restrict__ bbuf,
                         int* __restrict__ rowptr, int* __restrict__ csr, int N) {
  __shared__ int hist[BWID];
  __shared__ int sc[BWID];
  int b = blockIdx.x;
  int tid = threadIdx.x;  // 512
  int base_dst = b << BSH;
  int nd = min(BWID, N - base_dst);
  int s0 = boff[b], s1 = boff[b + 1];
  if (tid < BWID) hist[tid] = 0;
  __syncthreads();
  for (int j = s0 + tid; j < s1; j += 512)
    atomicAdd(&hist[bbuf[j] & (BWID - 1)], 1);
  __syncthreads();
  int v = 0;
  if (tid < BWID) { v = hist[tid]; sc[tid] = v; }
  __syncthreads();
  for (int off = 1; off < BWID; off <<= 1) {
    int add = 0;
    if (tid < BWID && tid >= off) add = sc[tid - off];
    __syncthreads();
    if (tid < BWID) sc[tid] += add;
    __syncthreads();
  }
  if (tid < nd) rowptr[base_dst + tid] = s0 + sc[tid] - v;
  __syncthreads();
  if (tid < BWID) hist[tid] = sc[tid] - v;
  __syncthreads();
  for (int j = s0 + tid; j < s1; j += 512) {
    int e = bbuf[j];
    int dl = e & (BWID - 1);
    int p = s0 + atomicAdd(&hist[dl], 1);
    csr[p] = (e >> BSH) << 5;   // src * 32 bytes
  }
}

// ---- h = in @ W (fp16, as packed in slot 15) ; ad_ fp32 (layer 0 only) ----
__global__ void k_transform(const float* __restrict__ in, int ld_in,
                            const float* __restrict__ W,
                            const float* __restrict__ a_s,
                            const float* __restrict__ a_d,
                            half_t* __restrict__ hp,
                            float* __restrict__ ad_,
                            int n_nodes) {
  __shared__ float Ws[FDIM * FDIM];
  __shared__ float asv[FDIM], adv[FDIM];
  int tid = threadIdx.x;
  if (tid < FDIM * FDIM) Ws[tid] = W[tid];
  if (tid < FDIM) { asv[tid] = a_s[tid]; adv[tid] = a_d[tid]; }
  __syncthreads();
  int n = blockIdx.x * blockDim.x + tid;
  if (n >= n_nodes) return;
  float xin[FDIM];
#pragma unroll
  for (int j = 0; j < FDIM; ++j) xin[j] = in[n * ld_in + j];
  float sa = 0.f, da = 0.f;
  half_t hrow[FPAD];
#pragma unroll
  for (int o = 0; o < FDIM; ++o) {
    float acc = 0.f;
#pragma unroll
    for (int k = 0; k < FDIM; ++k) acc += xin[k] * Ws[k * FDIM + o];
    hrow[o] = (half_t)acc;
    sa += acc * asv[o];
    da += acc * adv[o];
  }
  hrow[FDIM] = (half_t)sa;
  ad_[n] = da;
  float4 w0, w1;
  __builtin_memcpy(&w0, &hrow[0], 16);
  __builtin_memcpy(&w1, &hrow[8], 16);
  float4* dst = (float4*)(hp + (size_t)n * FPAD);
  dst[0] = w0;
  dst[1] = w1;
}

// ---- annotation-MLP stage rider: 8-way explicit ILP (R16 lesson: rider
// block lifetime = displacement window; R11 lesson: only explicit scalar
// loads produce loads-in-flight on this compiler) ----
__device__ __forceinline__ void mlp_rider(int g, int tid, int nthreads,
                                          const float* __restrict__ mIn,
                                          const float* __restrict__ mW,
                                          const float* __restrict__ mB,
                                          float* __restrict__ mOut,
                                          int Nout, int mAct,
                                          float* mins) {
  for (int k = tid; k < 300; k += nthreads) mins[k] = mIn[(size_t)g * 300 + k];
  __syncthreads();
  int j1 = tid;
  int j2 = tid + nthreads;
  bool p1 = (j1 < Nout), p2 = (j2 < Nout);
  if (!p1) return;
  float a0 = 0.f, a1 = 0.f, a2 = 0.f, a3 = 0.f;
  float a4 = 0.f, a5 = 0.f, a6 = 0.f, a7 = 0.f;
  float b0 = 0.f, b1 = 0.f, b2 = 0.f, b3 = 0.f;
  float b4 = 0.f, b5 = 0.f, b6 = 0.f, b7 = 0.f;
  int k = 0;
  for (; k + 7 < 300; k += 8) {
    float i0 = mins[k],     i1 = mins[k + 1], i2 = mins[k + 2], i3 = mins[k + 3];
    float i4 = mins[k + 4], i5 = mins[k + 5], i6 = mins[k + 6], i7 = mins[k + 7];
    float w0 = mW[k * Nout + j1];
    float w1 = mW[(k + 1) * Nout + j1];
    float w2 = mW[(k + 2) * Nout + j1];
    float w3 = mW[(k + 3) * Nout + j1];
    float w4 = mW[(k + 4) * Nout + j1];
    float w5 = mW[(k + 5) * Nout + j1];
    float w6 = mW[(k + 6) * Nout + j1];
    float w7 = mW[(k + 7) * Nout + j1];
    a0 += i0 * w0; a1 += i1 * w1; a2 += i2 * w2; a3 += i3 * w3;
    a4 += i4 * w4; a5 += i5 * w5; a6 += i6 * w6; a7 += i7 * w7;
    if (p2) {
      float v0 = mW[k * Nout + j2];
      float v1 = mW[(k + 1) * Nout + j2];
      float v2 = mW[(k + 2) * Nout + j2];
      float v3 = mW[(k + 3) * Nout + j2];
      float v4 = mW[(k + 4) * Nout + j2];
      float v5 = mW[(k + 5) * Nout + j2];
      float v6 = mW[(k + 6) * Nout + j2];
      float v7 = mW[(k + 7) * Nout + j2];
      b0 += i0 * v0; b1 += i1 * v1; b2 += i2 * v2; b3 += i3 * v3;
      b4 += i4 * v4; b5 += i5 * v5; b6 += i6 * v6; b7 += i7 * v7;
    }
  }
  for (; k < 300; ++k) {
    float ik = mins[k];
    a0 += ik * mW[k * Nout + j1];
    if (p2) b0 += ik * mW[k * Nout + j2];
  }
  float r1 = mB[j1] + ((a0 + a1) + (a2 + a3)) + ((a4 + a5) + (a6 + a7));
  if (mAct == 1) r1 = fmaxf(r1, 0.f);
  else if (mAct == 2) r1 = 1.f / (1.f + expf(-r1));
  mOut[(size_t)g * Nout + j1] = r1;
  if (p2) {
    float r2 = mB[j2] + ((b0 + b1) + (b2 + b3)) + ((b4 + b5) + (b6 + b7));
    if (mAct == 1) r2 = fmaxf(r2, 0.f);
    else if (mAct == 2) r2 = 1.f / (1.f + expf(-r2));
    mOut[(size_t)g * Nout + j2] = r2;
  }
}

// ---- fused GAT aggregate + FFN (+ next-layer transform) + MLP rider ----
// R18: 2-deep software pipeline at 16 edges/step. While computing step j,
// gathers for j+16 are in flight (offsets loaded a step earlier) and csr
// offsets for j+32 are being fetched. All indices clamped to re-1 -> every
// step uniform, masked weights; no tail loop. Breaks the serial
// csr->gather chain that left VALUBusy at 41% in R17.
__global__ void k_gat(const int* __restrict__ rowptr, const int* __restrict__ csrB,
                      const half_t* __restrict__ hp, const float* __restrict__ ad_,
                      const float* __restrict__ cb, const float* __restrict__ fW,
                      const float* __restrict__ fb,
                      const float* __restrict__ nW, const float* __restrict__ nas,
                      const float* __restrict__ nad,
                      half_t* __restrict__ hp2, float* __restrict__ ad2,
                      float* __restrict__ fout,
                      const float* __restrict__ mIn, const float* __restrict__ mW,
                      const float* __restrict__ mB, float* __restrict__ mOut,
                      int mNout, int mAct, int mlpG,
                      int n_nodes, int do_relu, int fuse) {
  __shared__ float Ws[FDIM * FDIM];
  __shared__ float W2s[FDIM * FDIM];
  __shared__ float cbv[FDIM], fbv[FDIM], as2v[FDIM], ad2v[FDIM];
  __shared__ float aggT[16][16];
  __shared__ float outT[16][16];
  __shared__ float mins[304];
  int tid = threadIdx.x;

  if ((int)blockIdx.x < mlpG) {
    mlp_rider(blockIdx.x, tid, blockDim.x, mIn, mW, mB, mOut, mNout, mAct, mins);
    return;
  }

  if (tid < FDIM * FDIM) Ws[tid] = fW[tid];
  if (tid < FDIM) { cbv[tid] = cb[tid]; fbv[tid] = fb[tid]; }
  if (fuse) {
    if (tid < FDIM * FDIM) W2s[tid] = nW[tid];
    if (tid < FDIM) { as2v[tid] = nas[tid]; ad2v[tid] = nad[tid]; }
  }
  __syncthreads();
  int dl = tid >> 4;          // local dst 0..15
  int f  = tid & 15;          // lane-in-group
  int e4 = f >> 2;            // edge slot 0..3
  int c  = f & 3;             // 4-half chunk 0..3 (chunk 3 holds slot 15 = sa)
  int d  = ((int)blockIdx.x - mlpG) * 16 + dl;
  float r0 = 0.f, r1 = 0.f, r2 = 0.f, r3 = 0.f;
  if (d < n_nodes) {
    int rs = rowptr[d], re = rowptr[d + 1];   // re > rs always (self loop)
    int rlast = re - 1;
    float adv = ad_[d];
    const char* hb = (const char*)hp;
    int co = c << 3;
    int srcl = f | 3;         // shfl source: c==3 lane of my edge slot
    float acc0 = 0.f, acc1 = 0.f, acc2 = 0.f, acc3 = 0.f, den = 0.f;

#define CLOAD(base, q0, q1, q2, q3)                              \
    {                                                            \
      int t0 = (base) + e4, t1 = t0 + 4, t2 = t0 + 8, t3 = t0 + 12; \
      q0 = csrB[t0 < re ? t0 : rlast];                           \
      q1 = csrB[t1 < re ? t1 : rlast];                           \
      q2 = csrB[t2 < re ? t2 : rlast];                           \
      q3 = csrB[t3 < re ? t3 : rlast];                           \
    }

    // prologue: offsets+gathers for step rs; offsets for step rs+16
    int oA0, oA1, oA2, oA3, oB0, oB1, oB2, oB3;
    CLOAD(rs, oA0, oA1, oA2, oA3);
    uint2 uA0 = *(const uint2*)(hb + oA0 + co);
    uint2 uA1 = *(const uint2*)(hb + oA1 + co);
    uint2 uA2 = *(const uint2*)(hb + oA2 + co);
    uint2 uA3 = *(const uint2*)(hb + oA3 + co);
    CLOAD(rs + 16, oB0, oB1, oB2, oB3);

    for (int j = rs; j < re; j += 16) {
      // issue gathers for [j+16, j+32)
      uint2 uB0 = *(const uint2*)(hb + oB0 + co);
      uint2 uB1 = *(const uint2*)(hb + oB1 + co);
      uint2 uB2 = *(const uint2*)(hb + oB2 + co);
      uint2 uB3 = *(const uint2*)(hb + oB3 + co);
      // prefetch offsets for [j+32, j+48)
      int oC0, oC1, oC2, oC3;
      CLOAD(j + 32, oC0, oC1, oC2, oC3);
      // compute edges [j, j+16) from uA*
      half_t ea[4], eb[4], ec[4], ed[4];
      __builtin_memcpy(ea, &uA0, 8);
      __builtin_memcpy(eb, &uA1, 8);
      __builtin_memcpy(ec, &uA2, 8);
      __builtin_memcpy(ed, &uA3, 8);
      float a0 = (float)ea[0], a1 = (float)ea[1], a2 = (float)ea[2], a3 = (float)ea[3];
      float b0 = (float)eb[0], b1 = (float)eb[1], b2 = (float)eb[2], b3 = (float)eb[3];
      float p0 = (float)ec[0], p1 = (float)ec[1], p2 = (float)ec[2], p3 = (float)ec[3];
      float q0 = (float)ed[0], q1 = (float)ed[1], q2 = (float)ed[2], q3 = (float)ed[3];
      float s0 = __shfl(a3, srcl, 16);
      float s1 = __shfl(b3, srcl, 16);
      float s2 = __shfl(p3, srcl, 16);
      float s3 = __shfl(q3, srcl, 16);
      int i0 = j + e4;
      float w0 = (i0      < re) ? __expf(leaky(s0 + adv)) : 0.f;
      float w1 = (i0 + 4  < re) ? __expf(leaky(s1 + adv)) : 0.f;
      float w2 = (i0 + 8  < re) ? __expf(leaky(s2 + adv)) : 0.f;
      float w3 = (i0 + 12 < re) ? __expf(leaky(s3 + adv)) : 0.f;
      den  += (w0 + w1) + (w2 + w3);
      acc0 += a0 * w0 + b0 * w1 + p0 * w2 + q0 * w3;
      acc1 += a1 * w0 + b1 * w1 + p1 * w2 + q1 * w3;
      acc2 += a2 * w0 + b2 * w1 + p2 * w2 + q2 * w3;
      acc3 += a3 * w0 + b3 * w1 + p3 * w2 + q3 * w3;
      // rotate pipeline
      uA0 = uB0; uA1 = uB1; uA2 = uB2; uA3 = uB3;
      oB0 = oC0; oB1 = oC1; oB2 = oC2; oB3 = oC3;
    }
#undef CLOAD
    // reduce across the 4 edge slots (xor bits 2..3 of lane-in-group)
    den  += __shfl_xor(den,  4, 16);
    acc0 += __shfl_xor(acc0, 4, 16);
    acc1 += __shfl_xor(acc1, 4, 16);
    acc2 += __shfl_xor(acc2, 4, 16);
    acc3 += __shfl_xor(acc3, 4, 16);
    den  += __shfl_xor(den,  8, 16);
    acc0 += __shfl_xor(acc0, 8, 16);
    acc1 += __shfl_xor(acc1, 8, 16);
    acc2 += __shfl_xor(acc2, 8, 16);
    acc3 += __shfl_xor(acc3, 8, 16);
    float inv = 1.f / (den + 1e-16f);
    r0 = acc0 * inv; r1 = acc1 * inv; r2 = acc2 * inv; r3 = acc3 * inv;
  }
  if (e4 == 0) {
    int base = c << 2;
    aggT[dl][base]     = r0 + cbv[base];
    aggT[dl][base + 1] = r1 + cbv[base + 1];
    aggT[dl][base + 2] = r2 + cbv[base + 2];
    aggT[dl][base + 3] = (base + 3 < FDIM) ? (r3 + cbv[base + 3]) : 0.f;
  }
  __syncthreads();
  int o = f;
  float ffn = 0.f;
  if (o < FDIM) {
    ffn = fbv[o];
#pragma unroll
    for (int k = 0; k < FDIM; ++k) ffn += aggT[dl][k] * Ws[k * FDIM + o];
    if (do_relu) ffn = fmaxf(ffn, 0.f);
  }
  if (!fuse) {
    if (d < n_nodes) fout[d * FPAD + o] = (o < FDIM) ? ffn : 0.f;
    return;
  }
  // ---- fused next-layer transform: h2 = out @ nW ; sa2/da2 reductions ----
  outT[dl][o] = ffn;   // o==15 lane wrote ffn=0
  __syncthreads();
  if (d < n_nodes) {
    float h2 = 0.f;
    if (o < FDIM) {
#pragma unroll
      for (int k = 0; k < FDIM; ++k) h2 += outT[dl][k] * W2s[k * FDIM + o];
    }
    float pa = (o < FDIM) ? h2 * as2v[o] : 0.f;
    float pd = (o < FDIM) ? h2 * ad2v[o] : 0.f;
#pragma unroll
    for (int k = 8; k; k >>= 1) {
      pa += __shfl_xor(pa, k, 16);
      pd += __shfl_xor(pd, k, 16);
    }
    hp2[(size_t)d * FPAD + o] = (half_t)((o < FDIM) ? h2 : pa);
    if (o == 0) ad2[d] = pd;
  }
}

// ---- pooling + s4 rider (xann = sigmoidActs @ aW4 + ab4) ----
__device__ __forceinline__ int lowerb(const int* __restrict__ a, int n, int key) {
  int lo = 0, hi = n;
  while (lo < hi) { int mid = (lo + hi) >> 1; if (a[mid] < key) lo = mid + 1; else hi = mid; }
  return lo;
}

__global__ void k_pool(const float* __restrict__ fout, const int* __restrict__ batch,
                       float* __restrict__ pooled,
                       const float* __restrict__ acts,
                       const float* __restrict__ aW4, const float* __restrict__ ab4,
                       float* __restrict__ xann,
                       int n_nodes, int Gn) {
  __shared__ float ss[256], sm[256];
  __shared__ float mins[304];
  int tid = threadIdx.x;
  if ((int)blockIdx.x < Gn) {
    mlp_rider(blockIdx.x, tid, blockDim.x, acts, aW4, ab4, xann, 45, 0, mins);
    return;
  }
  int g = blockIdx.x - Gn;
  int s = lowerb(batch, n_nodes, g);
  int e = lowerb(batch, n_nodes, g + 1);
  int f = tid & 15;
  float sum = 0.f, mx = -INFINITY;
  for (int n = s + (tid >> 4); n < e; n += 16) {
    float v = fout[n * FPAD + f];
    sum += v;
    mx = fmaxf(mx, v);
  }
  ss[tid] = sum; sm[tid] = mx;
  __syncthreads();
  for (int step = 128; step >= 16; step >>= 1) {
    if (tid < step) { ss[tid] += ss[tid + step]; sm[tid] = fmaxf(sm[tid], sm[tid + step]); }
    __syncthreads();
  }
  if (tid < FDIM) {
    float cnt = (float)(e - s);
    float sv = ss[tid];
    pooled[g * 45 + tid] = sv;
    pooled[g * 45 + 15 + tid] = sm[tid];
    pooled[g * 45 + 30 + tid] = sv / fmaxf(cnt, 1.f);
  }
}

// ---- head: z=[pooled,xann] -> relu(z@m1W+m1b) -> sigmoid(@m2W+m2b) ----
__global__ void k_final(const float* __restrict__ pooled, const float* __restrict__ xann,
                        const float* __restrict__ m1W, const float* __restrict__ m1b,
                        const float* __restrict__ m2W, const float* __restrict__ m2b,
                        float* __restrict__ out) {
  __shared__ float z[90];
  __shared__ float z2[90];
  __shared__ float ps[128];
  int g = blockIdx.x;
  int t = threadIdx.x;  // 128
  if (t < 45) z[t] = pooled[g * 45 + t];
  else if (t < 90) z[t] = xann[g * 45 + (t - 45)];
  __syncthreads();
  if (t < 90) {
    float a0 = 0.f, a1 = 0.f;
    for (int k = 0; k < 90; k += 2) {
      float w0 = m1W[k * 90 + t];
      float w1 = m1W[(k + 1) * 90 + t];
      a0 += z[k] * w0; a1 += z[k + 1] * w1;
    }
    z2[t] = fmaxf(m1b[t] + a0 + a1, 0.f);
  }
  __syncthreads();
  if (t < 90) ps[t] = z2[t] * m2W[t];
  else ps[t] = 0.f;
  __syncthreads();
  if (t < 64) {
    float v = ps[t] + ps[t + 64];
#pragma unroll
    for (int k2 = 32; k2; k2 >>= 1) v += __shfl_xor(v, k2, 64);
    if (t == 0) out[g] = 1.f / (1.f + expf(-(v + m2b[0])));
  }
}

extern "C" void kernel_launch(void* const* d_in, const int* in_sizes, int n_in,
                              void* d_out, int out_size, void* d_ws, size_t ws_size,
                              hipStream_t stream) {
  const float* x   = (const float*)d_in[0];
  const int* ei    = (const int*)d_in[1];
  const int* batch = (const int*)d_in[2];
  const float* xA  = (const float*)d_in[3];

  const int N = in_sizes[0] / FDIM;
  const int E = in_sizes[1] / 2;
  const int G = in_sizes[3] / 300;
  const int ET = E + N;
  const int NB = (N + BWID - 1) >> BSH;   // dst buckets (<=512 for N<=131072)

  const int* srcI = ei;
  const int* dstI = ei + E;

  // ---- workspace layout (4-byte words) ----
  float* ws = (float*)d_ws;
  size_t layerW = (size_t)34 * N;  // hpA(8N)+hpB(8N)+adA(N)+adB(N)+fout(16N)
  size_t uSize = layerW > (size_t)ET ? layerW : (size_t)ET;
  size_t off = 0;
  int*    bbuf = (int*)(ws + off);
  half_t* hpA  = (half_t*)(ws + off);
  half_t* hpB  = (half_t*)(ws + off + (size_t)8 * N);
  float*  adA  = ws + off + (size_t)16 * N;
  float*  adB  = ws + off + (size_t)17 * N;
  float*  fout = ws + off + (size_t)18 * N;
  off += uSize;
  int*   rowptr = (int*)(ws + off); off += N + 1;
  int*   csr    = (int*)(ws + off); off += (size_t)ET;
  int*   bcnt   = (int*)(ws + off); off += 516;
  int*   boff   = (int*)(ws + off); off += 516;
  int*   bcur   = (int*)(ws + off); off += 516;
  float* pooled = ws + off; off += (size_t)G * 45;
  float* a1     = ws + off; off += (size_t)G * 300;
  float* a2     = ws + off; off += (size_t)G * 300;
  float* xann   = ws + off; off += (size_t)G * 45;

  const int B = 256;
  const int gN = (N + B - 1) / B;

  // ---- bucketed CSR build (R15 two-pass: 43us proven; R16 single-pass lost) --
  k_zero<<<(NB + B - 1) / B, B, 0, stream>>>(bcnt, NB);
  k_bhist<<<HB_GRID, HB_BLK, 0, stream>>>(dstI, bcnt, ET, E, NB);
  k_bscan<<<1, 512, 0, stream>>>(bcnt, boff, bcur, rowptr, NB, N, ET);
  k_bpart<<<HB_GRID, HB_BLK, 0, stream>>>(srcI, dstI, bcur, bbuf, ET, E, NB);
  k_bbuild<<<NB, 512, 0, stream>>>(boff, bbuf, rowptr, csr, N);

  // ---- weights ----
  const float* cW1  = (const float*)d_in[4];
  const float* cas1 = (const float*)d_in[5];
  const float* cad1 = (const float*)d_in[6];
  const float* cb1  = (const float*)d_in[7];
  const float* fW1  = (const float*)d_in[8];
  const float* fb1  = (const float*)d_in[9];
  const float* cW2  = (const float*)d_in[10];
  const float* cas2 = (const float*)d_in[11];
  const float* cad2 = (const float*)d_in[12];
  const float* cb2  = (const float*)d_in[13];
  const float* fW2  = (const float*)d_in[14];
  const float* fb2  = (const float*)d_in[15];
  const float* cW3  = (const float*)d_in[16];
  const float* cas3 = (const float*)d_in[17];
  const float* cad3 = (const float*)d_in[18];
  const float* cb3  = (const float*)d_in[19];
  const float* fW3  = (const float*)d_in[20];
  const float* fb3  = (const float*)d_in[21];
  const float* m1W  = (const float*)d_in[22];
  const float* m1b  = (const float*)d_in[23];
  const float* aW1  = (const float*)d_in[24];
  const float* ab1  = (const float*)d_in[25];
  const float* aW2  = (const float*)d_in[26];
  const float* ab2  = (const float*)d_in[27];
  const float* aW3  = (const float*)d_in[28];
  const float* ab3  = (const float*)d_in[29];
  const float* aW4  = (const float*)d_in[30];
  const float* ab4  = (const float*)d_in[31];
  const float* m2W  = (const float*)d_in[32];
  const float* m2b  = (const float*)d_in[33];

  // ---- 3 GAT layers, each carrying one annotation-MLP stage (R15 placement) --
  const int gGat = (N + 15) / 16;
  k_transform<<<gN, B, 0, stream>>>(x, FDIM, cW1, cas1, cad1, hpA, adA, N);
  k_gat<<<gGat + G, B, 0, stream>>>(rowptr, csr, hpA, adA, cb1, fW1, fb1,
                                    cW2, cas2, cad2, hpB, adB, nullptr,
                                    xA, aW1, ab1, a1, 300, 1, G,
                                    N, 1, 1);
  k_gat<<<gGat + G, B, 0, stream>>>(rowptr, csr, hpB, adB, cb2, fW2, fb2,
                                    cW3, cas3, cad3, hpA, adA, nullptr,
                                    a1, aW2, ab2, a2, 300, 1, G,
                                    N, 1, 1);
  k_gat<<<gGat + G, B, 0, stream>>>(rowptr, csr, hpA, adA, cb3, fW3, fb3,
                                    nullptr, nullptr, nullptr, nullptr, nullptr, fout,
                                    a2, aW3, ab3, a1, 300, 2, G,
                                    N, 0, 0);

  // ---- pooling + s4 rider ----
  k_pool<<<2 * G, B, 0, stream>>>(fout, batch, pooled, a1, aW4, ab4, xann, N, G);

  // ---- head ----
  k_final<<<G, 128, 0, stream>>>(pooled, xann, m1W, m1b, m2W, m2b, (float*)d_out);
}

// Round 3
// 321.529 us; speedup vs baseline: 1.1238x; 1.0068x over previous
//
#include <hip/hip_runtime.h>
#include <hip/hip_bf16.h>
#include <math.h>

#define FDIM 15
#define FPAD 16
#define NEG_SLOPE 0.2f
// dst-buckets of 256 nodes each: bucket = dst >> 8, local = dst & 255
#define BSH 8
#define BWID 256
// R5/R9 lesson: per-(block,bucket) chunk contiguity rules. 256 blocks ->
// ~33 edges (132B) per chunk. 1024 thr/block supplies occupancy.
#define HB_GRID 256
#define HB_BLK 1024

typedef _Float16 half_t;

__device__ __forceinline__ float leaky(float e) {
  return fmaxf(NEG_SLOPE * e, e);   // valid for slope<1
}

__global__ void k_zero(int* __restrict__ p, int n) {
  int i = blockIdx.x * blockDim.x + threadIdx.x;
  if (i < n) p[i] = 0;
}

// ---- bucket histogram over all edges (incl. self loops) ----
// R19: also dumps the per-block histogram to bhistG so k_bpart can skip
// its duplicate first edge pass (same grid/stride => same edge set).
__global__ void k_bhist(const int* __restrict__ dstI, int* __restrict__ bcnt,
                        int* __restrict__ bhistG,
                        int n_tot, int n_real, int NB) {
  __shared__ int hist[512];
  int tid = threadIdx.x;
  for (int i = tid; i < NB; i += blockDim.x) hist[i] = 0;
  __syncthreads();
  int stride = gridDim.x * blockDim.x;
  for (int i = blockIdx.x * blockDim.x + tid; i < n_tot; i += stride) {
    int d = (i < n_real) ? dstI[i] : (i - n_real);
    atomicAdd(&hist[d >> BSH], 1);
  }
  __syncthreads();
  for (int i = tid; i < NB; i += blockDim.x) {
    int h = hist[i];
    bhistG[blockIdx.x * 512 + i] = h;
    if (h) atomicAdd(&bcnt[i], h);
  }
}

// ---- exclusive scan of bucket counts (single block, 512 thr) ----
__global__ void k_bscan(const int* __restrict__ bcnt, int* __restrict__ boff,
                        int* __restrict__ bcur, int* __restrict__ rowptr,
                        int NB, int N, int total) {
  __shared__ int s[512];
  int tid = threadIdx.x;
  int v = (tid < NB) ? bcnt[tid] : 0;
  s[tid] = v;
  __syncthreads();
  for (int off = 1; off < 512; off <<= 1) {
    int add = (tid >= off) ? s[tid - off] : 0;
    __syncthreads();
    s[tid] += add;
    __syncthreads();
  }
  if (tid < NB) { int e = s[tid] - v; boff[tid] = e; bcur[tid] = e; }
  if (tid == NB - 1) boff[NB] = s[tid];
  if (tid == 0) rowptr[N] = total;
}

// ---- partition edges into dst-buckets, packed (src<<8 | dst&255) ----
// R19: first pass removed; per-block hist comes from bhistG.
__global__ void k_bpart(const int* __restrict__ srcI, const int* __restrict__ dstI,
                        int* __restrict__ bcur, int* __restrict__ bbuf,
                        const int* __restrict__ bhistG,
                        int n_tot, int n_real, int NB) {
  __shared__ int hist[512];
  __shared__ int base[512];
  int tid = threadIdx.x;
  for (int i = tid; i < NB; i += blockDim.x) {
    int h = bhistG[blockIdx.x * 512 + i];
    base[i] = h ? atomicAdd(&bcur[i], h) : 0;
    hist[i] = 0;
  }
  __syncthreads();
  int stride = gridDim.x * blockDim.x;
  int g0 = blockIdx.x * blockDim.x + tid;
  for (int i = g0; i < n_tot; i += stride) {
    int s, d;
    if (i < n_real) { s = srcI[i]; d = dstI[i]; }
    else { s = d = i - n_real; }
    int b = d >> BSH;
    int p = base[b] + atomicAdd(&hist[b], 1);
    bbuf[p] = (s << BSH) | (d & (BWID - 1));
  }
}

// ---- per-bucket: per-dst hist -> scan -> rowptr + csr scatter (512 thr) ----
// csr stores PRE-SCALED byte offsets (src*32) for k_gat's hp gathers.
__global__ void k_bbuild(const int* __restrict__ boff, const int* __restrict__ bbuf,
                         int* __restrict__ rowptr, int* __restrict__ csr, int N) {
  __shared__ int hist[BWID];
  __shared__ int sc[BWID];
  int b = blockIdx.x;
  int tid = threadIdx.x;  // 512
  int base_dst = b << BSH;
  int nd = min(BWID, N - base_dst);
  int s0 = boff[b], s1 = boff[b + 1];
  if (tid < BWID) hist[tid] = 0;
  __syncthreads();
  for (int j = s0 + tid; j < s1; j += 512)
    atomicAdd(&hist[bbuf[j] & (BWID - 1)], 1);
  __syncthreads();
  int v = 0;
  if (tid < BWID) { v = hist[tid]; sc[tid] = v; }
  __syncthreads();
  for (int off = 1; off < BWID; off <<= 1) {
    int add = 0;
    if (tid < BWID && tid >= off) add = sc[tid - off];
    __syncthreads();
    if (tid < BWID) sc[tid] += add;
    __syncthreads();
  }
  if (tid < nd) rowptr[base_dst + tid] = s0 + sc[tid] - v;
  __syncthreads();
  if (tid < BWID) hist[tid] = sc[tid] - v;
  __syncthreads();
  for (int j = s0 + tid; j < s1; j += 512) {
    int e = bbuf[j];
    int dl = e & (BWID - 1);
    int p = s0 + atomicAdd(&hist[dl], 1);
    csr[p] = (e >> BSH) << 5;   // src * 32 bytes
  }
}

// ---- h = in @ W (fp16, as packed in slot 15) ; ad_ fp32 (layer 0 only) ----
__global__ void k_transform(const float* __restrict__ in, int ld_in,
                            const float* __restrict__ W,
                            const float* __restrict__ a_s,
                            const float* __restrict__ a_d,
                            half_t* __restrict__ hp,
                            float* __restrict__ ad_,
                            int n_nodes) {
  __shared__ float Ws[FDIM * FDIM];
  __shared__ float asv[FDIM], adv[FDIM];
  int tid = threadIdx.x;
  if (tid < FDIM * FDIM) Ws[tid] = W[tid];
  if (tid < FDIM) { asv[tid] = a_s[tid]; adv[tid] = a_d[tid]; }
  __syncthreads();
  int n = blockIdx.x * blockDim.x + tid;
  if (n >= n_nodes) return;
  float xin[FDIM];
#pragma unroll
  for (int j = 0; j < FDIM; ++j) xin[j] = in[n * ld_in + j];
  float sa = 0.f, da = 0.f;
  half_t hrow[FPAD];
#pragma unroll
  for (int o = 0; o < FDIM; ++o) {
    float acc = 0.f;
#pragma unroll
    for (int k = 0; k < FDIM; ++k) acc += xin[k] * Ws[k * FDIM + o];
    hrow[o] = (half_t)acc;
    sa += acc * asv[o];
    da += acc * adv[o];
  }
  hrow[FDIM] = (half_t)sa;
  ad_[n] = da;
  float4 w0, w1;
  __builtin_memcpy(&w0, &hrow[0], 16);
  __builtin_memcpy(&w1, &hrow[8], 16);
  float4* dst = (float4*)(hp + (size_t)n * FPAD);
  dst[0] = w0;
  dst[1] = w1;
}

// ---- annotation-MLP stage rider: 8-way explicit ILP (R16 lesson: rider
// block lifetime = displacement window; R11 lesson: only explicit scalar
// loads produce loads-in-flight on this compiler) ----
__device__ __forceinline__ void mlp_rider(int g, int tid, int nthreads,
                                          const float* __restrict__ mIn,
                                          const float* __restrict__ mW,
                                          const float* __restrict__ mB,
                                          float* __restrict__ mOut,
                                          int Nout, int mAct,
                                          float* mins) {
  for (int k = tid; k < 300; k += nthreads) mins[k] = mIn[(size_t)g * 300 + k];
  __syncthreads();
  int j1 = tid;
  int j2 = tid + nthreads;
  bool p1 = (j1 < Nout), p2 = (j2 < Nout);
  if (!p1) return;
  float a0 = 0.f, a1 = 0.f, a2 = 0.f, a3 = 0.f;
  float a4 = 0.f, a5 = 0.f, a6 = 0.f, a7 = 0.f;
  float b0 = 0.f, b1 = 0.f, b2 = 0.f, b3 = 0.f;
  float b4 = 0.f, b5 = 0.f, b6 = 0.f, b7 = 0.f;
  int k = 0;
  for (; k + 7 < 300; k += 8) {
    float i0 = mins[k],     i1 = mins[k + 1], i2 = mins[k + 2], i3 = mins[k + 3];
    float i4 = mins[k + 4], i5 = mins[k + 5], i6 = mins[k + 6], i7 = mins[k + 7];
    float w0 = mW[k * Nout + j1];
    float w1 = mW[(k + 1) * Nout + j1];
    float w2 = mW[(k + 2) * Nout + j1];
    float w3 = mW[(k + 3) * Nout + j1];
    float w4 = mW[(k + 4) * Nout + j1];
    float w5 = mW[(k + 5) * Nout + j1];
    float w6 = mW[(k + 6) * Nout + j1];
    float w7 = mW[(k + 7) * Nout + j1];
    a0 += i0 * w0; a1 += i1 * w1; a2 += i2 * w2; a3 += i3 * w3;
    a4 += i4 * w4; a5 += i5 * w5; a6 += i6 * w6; a7 += i7 * w7;
    if (p2) {
      float v0 = mW[k * Nout + j2];
      float v1 = mW[(k + 1) * Nout + j2];
      float v2 = mW[(k + 2) * Nout + j2];
      float v3 = mW[(k + 3) * Nout + j2];
      float v4 = mW[(k + 4) * Nout + j2];
      float v5 = mW[(k + 5) * Nout + j2];
      float v6 = mW[(k + 6) * Nout + j2];
      float v7 = mW[(k + 7) * Nout + j2];
      b0 += i0 * v0; b1 += i1 * v1; b2 += i2 * v2; b3 += i3 * v3;
      b4 += i4 * v4; b5 += i5 * v5; b6 += i6 * v6; b7 += i7 * v7;
    }
  }
  for (; k < 300; ++k) {
    float ik = mins[k];
    a0 += ik * mW[k * Nout + j1];
    if (p2) b0 += ik * mW[k * Nout + j2];
  }
  float r1 = mB[j1] + ((a0 + a1) + (a2 + a3)) + ((a4 + a5) + (a6 + a7));
  if (mAct == 1) r1 = fmaxf(r1, 0.f);
  else if (mAct == 2) r1 = 1.f / (1.f + expf(-r1));
  mOut[(size_t)g * Nout + j1] = r1;
  if (p2) {
    float r2 = mB[j2] + ((b0 + b1) + (b2 + b3)) + ((b4 + b5) + (b6 + b7));
    if (mAct == 1) r2 = fmaxf(r2, 0.f);
    else if (mAct == 2) r2 = 1.f / (1.f + expf(-r2));
    mOut[(size_t)g * Nout + j2] = r2;
  }
}

// ---- fused GAT aggregate + FFN (+ next-layer transform) + MLP rider ----
// R19: one-lane-per-edge. Lane f owns edge j+f whole: 1 coalesced csr
// load, 2x dwordx4 row gather (32B), sa local (no per-edge shfl), weight
// computed once per edge. Row epilogue: 15-shfl halving butterfly; lane f
// ends with feature brev4(f); slot 15 carries den. cb-bias and 1/den are
// folded into the FFN via cbW[o] = sum_k cb[k]*W[k][o].
__global__ void k_gat(const int* __restrict__ rowptr, const int* __restrict__ csrB,
                      const half_t* __restrict__ hp, const float* __restrict__ ad_,
                      const float* __restrict__ cb, const float* __restrict__ fW,
                      const float* __restrict__ fb,
                      const float* __restrict__ nW, const float* __restrict__ nas,
                      const float* __restrict__ nad,
                      half_t* __restrict__ hp2, float* __restrict__ ad2,
                      float* __restrict__ fout,
                      const float* __restrict__ mIn, const float* __restrict__ mW,
                      const float* __restrict__ mB, float* __restrict__ mOut,
                      int mNout, int mAct, int mlpG,
                      int n_nodes, int do_relu, int fuse) {
  __shared__ float Ws[FDIM * FDIM];
  __shared__ float W2s[FDIM * FDIM];
  __shared__ float cbv[FDIM], fbv[FDIM], as2v[FDIM], ad2v[FDIM];
  __shared__ float cbW[16];
  __shared__ float aggT[16][16];
  __shared__ float outT[16][16];
  __shared__ float mins[304];
  int tid = threadIdx.x;

  if ((int)blockIdx.x < mlpG) {
    mlp_rider(blockIdx.x, tid, blockDim.x, mIn, mW, mB, mOut, mNout, mAct, mins);
    return;
  }

  if (tid < FDIM * FDIM) Ws[tid] = fW[tid];
  if (tid < FDIM) { cbv[tid] = cb[tid]; fbv[tid] = fb[tid]; }
  if (fuse) {
    if (tid < FDIM * FDIM) W2s[tid] = nW[tid];
    if (tid < FDIM) { as2v[tid] = nas[tid]; ad2v[tid] = nad[tid]; }
  }
  __syncthreads();
  // fold cb into FFN: cbW[o] = sum_k cb[k] * W[k][o]
  if (tid < 16) {
    float s = 0.f;
    if (tid < FDIM) {
#pragma unroll
      for (int k = 0; k < FDIM; ++k) s += cbv[k] * Ws[k * FDIM + tid];
    }
    cbW[tid] = s;
  }
  int dl = tid >> 4;          // local dst 0..15
  int f  = tid & 15;          // lane-in-group = edge slot
  int d  = ((int)blockIdx.x - mlpG) * 16 + dl;
  if (d < n_nodes) {
    int rs = rowptr[d], re = rowptr[d + 1];   // re > rs always (self loop)
    int rlast = re - 1;
    float adv = ad_[d];
    const char* hb = (const char*)hp;
    float acc[16];
#pragma unroll
    for (int k = 0; k < 16; ++k) acc[k] = 0.f;

    // prologue: offsets+gathers for step 0; offsets for step 1
    int i0 = rs + f;
    int oA = csrB[i0 < re ? i0 : rlast];
    uint4 aLo = *(const uint4*)(hb + oA);
    uint4 aHi = *(const uint4*)(hb + oA + 16);
    int i1 = i0 + 16;
    int oB = csrB[i1 < re ? i1 : rlast];

    for (int j = rs; j < re; j += 16) {
      // gathers for next step
      uint4 bLo = *(const uint4*)(hb + oB);
      uint4 bHi = *(const uint4*)(hb + oB + 16);
      // offsets for step after next
      int i2 = j + 32 + f;
      int oC = csrB[i2 < re ? i2 : rlast];
      // compute current edge j+f
      half_t hv[16];
      __builtin_memcpy(hv, &aLo, 16);
      __builtin_memcpy(hv + 8, &aHi, 16);
      float sa = (float)hv[15];
      float w = (j + f < re) ? __expf(leaky(sa + adv)) : 0.f;
#pragma unroll
      for (int k = 0; k < FDIM; ++k) acc[k] += w * (float)hv[k];
      acc[15] += w;   // den rides in slot 15
      // rotate pipeline
      aLo = bLo; aHi = bHi; oB = oC;
    }

    // 16-lane halving butterfly: lane f ends with sum over lanes of
    // feature brev4(f) in acc[0] (slot 15 = den lands on lane 15).
    {
      bool hi = (f & 1);
#pragma unroll
      for (int i = 0; i < 8; ++i) {
        float send = hi ? acc[i] : acc[8 + i];
        float got = __shfl_xor(send, 1, 16);
        acc[i] = (hi ? acc[8 + i] : acc[i]) + got;
      }
      hi = (f & 2);
#pragma unroll
      for (int i = 0; i < 4; ++i) {
        float send = hi ? acc[i] : acc[4 + i];
        float got = __shfl_xor(send, 2, 16);
        acc[i] = (hi ? acc[4 + i] : acc[i]) + got;
      }
      hi = (f & 4);
#pragma unroll
      for (int i = 0; i < 2; ++i) {
        float send = hi ? acc[i] : acc[2 + i];
        float got = __shfl_xor(send, 4, 16);
        acc[i] = (hi ? acc[2 + i] : acc[i]) + got;
      }
      hi = (f & 8);
      {
        float send = hi ? acc[0] : acc[1];
        float got = __shfl_xor(send, 8, 16);
        acc[0] = (hi ? acc[1] : acc[0]) + got;
      }
    }
    int fb = ((f & 1) << 3) | ((f & 2) << 1) | ((f & 4) >> 1) | ((f & 8) >> 3);
    aggT[dl][fb] = acc[0];   // raw weighted sums; [15] = den
  }
  __syncthreads();
  int o = f;
  float ffn = 0.f;
  if (o < FDIM && d < n_nodes) {
    float inv = 1.f / (aggT[dl][15] + 1e-16f);
    float s = 0.f;
#pragma unroll
    for (int k = 0; k < FDIM; ++k) s += aggT[dl][k] * Ws[k * FDIM + o];
    ffn = fbv[o] + cbW[o] + s * inv;
    if (do_relu) ffn = fmaxf(ffn, 0.f);
  }
  if (!fuse) {
    if (d < n_nodes) fout[d * FPAD + o] = (o < FDIM) ? ffn : 0.f;
    return;
  }
  // ---- fused next-layer transform: h2 = out @ nW ; sa2/da2 reductions ----
  outT[dl][o] = ffn;   // o==15 lane wrote ffn=0; invalid-d rows unused
  __syncthreads();
  if (d < n_nodes) {
    float h2 = 0.f;
    if (o < FDIM) {
#pragma unroll
      for (int k = 0; k < FDIM; ++k) h2 += outT[dl][k] * W2s[k * FDIM + o];
    }
    float pa = (o < FDIM) ? h2 * as2v[o] : 0.f;
    float pd = (o < FDIM) ? h2 * ad2v[o] : 0.f;
#pragma unroll
    for (int k = 8; k; k >>= 1) {
      pa += __shfl_xor(pa, k, 16);
      pd += __shfl_xor(pd, k, 16);
    }
    hp2[(size_t)d * FPAD + o] = (half_t)((o < FDIM) ? h2 : pa);
    if (o == 0) ad2[d] = pd;
  }
}

// ---- pooling + s4 rider (xann = sigmoidActs @ aW4 + ab4) ----
__device__ __forceinline__ int lowerb(const int* __restrict__ a, int n, int key) {
  int lo = 0, hi = n;
  while (lo < hi) { int mid = (lo + hi) >> 1; if (a[mid] < key) lo = mid + 1; else hi = mid; }
  return lo;
}

__global__ void k_pool(const float* __restrict__ fout, const int* __restrict__ batch,
                       float* __restrict__ pooled,
                       const float* __restrict__ acts,
                       const float* __restrict__ aW4, const float* __restrict__ ab4,
                       float* __restrict__ xann,
                       int n_nodes, int Gn) {
  __shared__ float ss[256], sm[256];
  __shared__ float mins[304];
  int tid = threadIdx.x;
  if ((int)blockIdx.x < Gn) {
    mlp_rider(blockIdx.x, tid, blockDim.x, acts, aW4, ab4, xann, 45, 0, mins);
    return;
  }
  int g = blockIdx.x - Gn;
  int s = lowerb(batch, n_nodes, g);
  int e = lowerb(batch, n_nodes, g + 1);
  int f = tid & 15;
  float sum = 0.f, mx = -INFINITY;
  for (int n = s + (tid >> 4); n < e; n += 16) {
    float v = fout[n * FPAD + f];
    sum += v;
    mx = fmaxf(mx, v);
  }
  ss[tid] = sum; sm[tid] = mx;
  __syncthreads();
  for (int step = 128; step >= 16; step >>= 1) {
    if (tid < step) { ss[tid] += ss[tid + step]; sm[tid] = fmaxf(sm[tid], sm[tid + step]); }
    __syncthreads();
  }
  if (tid < FDIM) {
    float cnt = (float)(e - s);
    float sv = ss[tid];
    pooled[g * 45 + tid] = sv;
    pooled[g * 45 + 15 + tid] = sm[tid];
    pooled[g * 45 + 30 + tid] = sv / fmaxf(cnt, 1.f);
  }
}

// ---- head: z=[pooled,xann] -> relu(z@m1W+m1b) -> sigmoid(@m2W+m2b) ----
__global__ void k_final(const float* __restrict__ pooled, const float* __restrict__ xann,
                        const float* __restrict__ m1W, const float* __restrict__ m1b,
                        const float* __restrict__ m2W, const float* __restrict__ m2b,
                        float* __restrict__ out) {
  __shared__ float z[90];
  __shared__ float z2[90];
  __shared__ float ps[128];
  int g = blockIdx.x;
  int t = threadIdx.x;  // 128
  if (t < 45) z[t] = pooled[g * 45 + t];
  else if (t < 90) z[t] = xann[g * 45 + (t - 45)];
  __syncthreads();
  if (t < 90) {
    float a0 = 0.f, a1 = 0.f;
    for (int k = 0; k < 90; k += 2) {
      float w0 = m1W[k * 90 + t];
      float w1 = m1W[(k + 1) * 90 + t];
      a0 += z[k] * w0; a1 += z[k + 1] * w1;
    }
    z2[t] = fmaxf(m1b[t] + a0 + a1, 0.f);
  }
  __syncthreads();
  if (t < 90) ps[t] = z2[t] * m2W[t];
  else ps[t] = 0.f;
  __syncthreads();
  if (t < 64) {
    float v = ps[t] + ps[t + 64];
#pragma unroll
    for (int k2 = 32; k2; k2 >>= 1) v += __shfl_xor(v, k2, 64);
    if (t == 0) out[g] = 1.f / (1.f + expf(-(v + m2b[0])));
  }
}

extern "C" void kernel_launch(void* const* d_in, const int* in_sizes, int n_in,
                              void* d_out, int out_size, void* d_ws, size_t ws_size,
                              hipStream_t stream) {
  const float* x   = (const float*)d_in[0];
  const int* ei    = (const int*)d_in[1];
  const int* batch = (const int*)d_in[2];
  const float* xA  = (const float*)d_in[3];

  const int N = in_sizes[0] / FDIM;
  const int E = in_sizes[1] / 2;
  const int G = in_sizes[3] / 300;
  const int ET = E + N;
  const int NB = (N + BWID - 1) >> BSH;   // dst buckets (<=512 for N<=131072)

  const int* srcI = ei;
  const int* dstI = ei + E;

  // ---- workspace layout (4-byte words) ----
  float* ws = (float*)d_ws;
  size_t layerW = (size_t)34 * N;  // hpA(8N)+hpB(8N)+adA(N)+adB(N)+fout(16N)
  size_t uSize = layerW > (size_t)ET ? layerW : (size_t)ET;
  size_t off = 0;
  int*    bbuf = (int*)(ws + off);
  half_t* hpA  = (half_t*)(ws + off);
  half_t* hpB  = (half_t*)(ws + off + (size_t)8 * N);
  float*  adA  = ws + off + (size_t)16 * N;
  float*  adB  = ws + off + (size_t)17 * N;
  float*  fout = ws + off + (size_t)18 * N;
  off += uSize;
  int*   rowptr = (int*)(ws + off); off += N + 1;
  int*   csr    = (int*)(ws + off); off += (size_t)ET;
  int*   bcnt   = (int*)(ws + off); off += 516;
  int*   boff   = (int*)(ws + off); off += 516;
  int*   bcur   = (int*)(ws + off); off += 516;
  int*   bhistG = (int*)(ws + off); off += (size_t)512 * HB_GRID;
  float* pooled = ws + off; off += (size_t)G * 45;
  float* a1     = ws + off; off += (size_t)G * 300;
  float* a2     = ws + off; off += (size_t)G * 300;
  float* xann   = ws + off; off += (size_t)G * 45;

  const int B = 256;
  const int gN = (N + B - 1) / B;

  // ---- bucketed CSR build (R15 two-pass; R19 bhist->bpart hist reuse) ----
  k_zero<<<(NB + B - 1) / B, B, 0, stream>>>(bcnt, NB);
  k_bhist<<<HB_GRID, HB_BLK, 0, stream>>>(dstI, bcnt, bhistG, ET, E, NB);
  k_bscan<<<1, 512, 0, stream>>>(bcnt, boff, bcur, rowptr, NB, N, ET);
  k_bpart<<<HB_GRID, HB_BLK, 0, stream>>>(srcI, dstI, bcur, bbuf, bhistG, ET, E, NB);
  k_bbuild<<<NB, 512, 0, stream>>>(boff, bbuf, rowptr, csr, N);

  // ---- weights ----
  const float* cW1  = (const float*)d_in[4];
  const float* cas1 = (const float*)d_in[5];
  const float* cad1 = (const float*)d_in[6];
  const float* cb1  = (const float*)d_in[7];
  const float* fW1  = (const float*)d_in[8];
  const float* fb1  = (const float*)d_in[9];
  const float* cW2  = (const float*)d_in[10];
  const float* cas2 = (const float*)d_in[11];
  const float* cad2 = (const float*)d_in[12];
  const float* cb2  = (const float*)d_in[13];
  const float* fW2  = (const float*)d_in[14];
  const float* fb2  = (const float*)d_in[15];
  const float* cW3  = (const float*)d_in[16];
  const float* cas3 = (const float*)d_in[17];
  const float* cad3 = (const float*)d_in[18];
  const float* cb3  = (const float*)d_in[19];
  const float* fW3  = (const float*)d_in[20];
  const float* fb3  = (const float*)d_in[21];
  const float* m1W  = (const float*)d_in[22];
  const float* m1b  = (const float*)d_in[23];
  const float* aW1  = (const float*)d_in[24];
  const float* ab1  = (const float*)d_in[25];
  const float* aW2  = (const float*)d_in[26];
  const float* ab2  = (const float*)d_in[27];
  const float* aW3  = (const float*)d_in[28];
  const float* ab3  = (const float*)d_in[29];
  const float* aW4  = (const float*)d_in[30];
  const float* ab4  = (const float*)d_in[31];
  const float* m2W  = (const float*)d_in[32];
  const float* m2b  = (const float*)d_in[33];

  // ---- 3 GAT layers, each carrying one annotation-MLP stage (R15 placement) --
  const int gGat = (N + 15) / 16;
  k_transform<<<gN, B, 0, stream>>>(x, FDIM, cW1, cas1, cad1, hpA, adA, N);
  k_gat<<<gGat + G, B, 0, stream>>>(rowptr, csr, hpA, adA, cb1, fW1, fb1,
                                    cW2, cas2, cad2, hpB, adB, nullptr,
                                    xA, aW1, ab1, a1, 300, 1, G,
                                    N, 1, 1);
  k_gat<<<gGat + G, B, 0, stream>>>(rowptr, csr, hpB, adB, cb2, fW2, fb2,
                                    cW3, cas3, cad3, hpA, adA, nullptr,
                                    a1, aW2, ab2, a2, 300, 1, G,
                                    N, 1, 1);
  k_gat<<<gGat + G, B, 0, stream>>>(rowptr, csr, hpA, adA, cb3, fW3, fb3,
                                    nullptr, nullptr, nullptr, nullptr, nullptr, fout,
                                    a2, aW3, ab3, a1, 300, 2, G,
                                    N, 0, 0);

  // ---- pooling + s4 rider ----
  k_pool<<<2 * G, B, 0, stream>>>(fout, batch, pooled, a1, aW4, ab4, xann, N, G);

  // ---- head ----
  k_final<<<G, 128, 0, stream>>>(pooled, xann, m1W, m1b, m2W, m2b, (float*)d_out);
}